// Round 13
// baseline (259.472 us; speedup 1.0000x reference)
//
#include <hip/hip_runtime.h>

typedef unsigned short u16;
typedef __attribute__((ext_vector_type(8))) short v8s;   // 8 x bf16 MFMA operand
typedef __attribute__((ext_vector_type(4))) float v4f;   // MFMA accumulator

__device__ __forceinline__ u16 f2bf(float f) {
  unsigned u = __float_as_uint(f);
  u += 0x7FFF + ((u >> 16) & 1);   // RNE
  return (u16)(u >> 16);
}

// pack two floats -> {hi.bf16, lo.bf16} u32 (round-half-up, fine at this scale)
__device__ __forceinline__ unsigned pk2bf(float lo, float hi) {
  unsigned a = __float_as_uint(lo) + 0x8000u;
  unsigned b = __float_as_uint(hi) + 0x8000u;
  return __builtin_amdgcn_perm(b, a, 0x07060302);
}

__device__ __forceinline__ v4f zero4() {
  v4f z; z[0] = 0.f; z[1] = 0.f; z[2] = 0.f; z[3] = 0.f; return z;
}

__device__ __forceinline__ void async16(const u16* g, u16* l) {
  __builtin_amdgcn_global_load_lds(
      (const __attribute__((address_space(1))) unsigned int*)g,
      (__attribute__((address_space(3))) unsigned int*)l, 16, 0, 0);
}

// reduce x to [-pi,pi] then native sin/cos (v_sin valid range)
__device__ __forceinline__ void fast_sincos(float x, float* s, float* c) {
  float k = rintf(x * 0.15915494309189535f);
  float r = __builtin_fmaf(k, -6.28125f, x);
  r = __builtin_fmaf(k, -0.0019353071795864769f, r);
  *s = __sinf(r);
  *c = __cosf(r);
}

#define ATTN_SCL (0.125f * 1.4426950408889634f)  // 1/sqrt(64) * log2(e), folded into Q

// ---------------- fused fp32 -> bf16 cast of all three inputs ----------------
__global__ __launch_bounds__(256) void cast_all_k(const float* __restrict__ x,
                                                  const float* __restrict__ wq,
                                                  const float* __restrict__ wo,
                                                  u16* __restrict__ dst) {
  int i = blockIdx.x * 256 + threadIdx.x;
  const float4* s;
  int si;
  if (i < 2097152) { s = (const float4*)x;  si = i; }
  else if (i < 2883584) { s = (const float4*)wq; si = i - 2097152; }
  else { s = (const float4*)wo; si = i - 2883584; }
  float4 v = s[si];
  ((ushort4*)dst)[i] = make_ushort4(f2bf(v.x), f2bf(v.y), f2bf(v.z), f2bf(v.w));
}

// LDS bank swizzle (proven in-session): 16B granule g of row r lives at slot
// g^(r&7); staging loads global granule (slot^(r&7)) into linear LDS slot.

// ---------------- 128x128 GEMM mainloop ----------------
// C(128x128) = A[M,K] @ B[N,K]^T   (both bf16 row-major, K multiple of 64)
__device__ __forceinline__ void gemm_core(const u16* __restrict__ A,
                                          const u16* __restrict__ B, int K,
                                          int row0, int col0, u16* As, u16* Bs,
                                          v4f acc[4][4]) {
  const int tid = threadIdx.x;
  const int lane = tid & 63;
  const int wm = (tid >> 7) & 1;
  const int wn = (tid >> 6) & 1;
  const int ln = lane & 15, quad = lane >> 4;
#pragma unroll
  for (int i = 0; i < 4; ++i)
#pragma unroll
    for (int j = 0; j < 4; ++j) acc[i][j] = zero4();
  const int rA = tid >> 3;
  const int cA = (((tid & 7) ^ (rA & 7)) << 3);
  for (int kt = 0; kt < K; kt += 64) {
#pragma unroll
    for (int i = 0; i < 4; ++i) {
      async16(A + (size_t)(row0 + i * 32 + rA) * K + kt + cA, As + i * 2048 + tid * 8);
      async16(B + (size_t)(col0 + i * 32 + rA) * K + kt + cA, Bs + i * 2048 + tid * 8);
    }
    __syncthreads();
#pragma unroll
    for (int kk = 0; kk < 2; ++kk) {
      const int go = (((kk * 4 + quad) ^ (ln & 7)) << 3);
      v8s af[4], bfr[4];
#pragma unroll
      for (int i = 0; i < 4; ++i) {
        af[i]  = *(const v8s*)(As + (wm * 64 + i * 16 + ln) * 64 + go);
        bfr[i] = *(const v8s*)(Bs + (wn * 64 + i * 16 + ln) * 64 + go);
      }
      __builtin_amdgcn_s_setprio(1);
#pragma unroll
      for (int i = 0; i < 4; ++i)
#pragma unroll
        for (int j = 0; j < 4; ++j)
          acc[i][j] = __builtin_amdgcn_mfma_f32_16x16x32_bf16(af[i], bfr[j], acc[i][j], 0, 0, 0);
      __builtin_amdgcn_s_setprio(0);
    }
    __syncthreads();
  }
}

// ---------------- QKV GEMM + fused RoPE/reshape epilogue ----------------
// r13: V^T output now goes through an LDS transpose so global stores are
// contiguous 128 B/thread (was: 64 scalar 2-byte stores at 4 KB stride per
// thread -> sector-fragmented, issue-bound). Q/K path unchanged.
__global__ __launch_bounds__(256) void gemm_qkv_rope(const u16* __restrict__ A,
                                                     const u16* __restrict__ B,
                                                     u16* __restrict__ Qh,
                                                     u16* __restrict__ Kh,
                                                     u16* __restrict__ Vt) {
  __shared__ __align__(16) u16 Ls[16384];   // 32 KB: gemm As/Bs, then V-transpose
  u16* As = Ls;
  u16* Bs = Ls + 8192;
  v4f acc[4][4];
  const int row0 = blockIdx.x * 128, col0 = blockIdx.y * 128;
  gemm_core(A, B, 1024, row0, col0, As, Bs, acc);
  const int tid = threadIdx.x, lane = tid & 63;
  const int wm = (tid >> 7) & 1, wn = (tid >> 6) & 1;
  const int ln = lane & 15, quad = lane >> 4;
  const int colbase = col0 + wn * 64;       // 64-aligned => one head per wave
  const int seg = colbase >> 10;            // 0=q 1=k 2=v (block-uniform: col0 % 128 == 0)
  const int h = (colbase & 1023) >> 6;
  if (seg < 2) {
    u16* dst = (seg == 0) ? Qh : Kh;
    const float oscl = (seg == 0) ? ATTN_SCL : 1.0f;
#pragma unroll
    for (int i = 0; i < 4; ++i) {
#pragma unroll
      for (int r = 0; r < 4; ++r) {
        int row = row0 + wm * 64 + i * 16 + quad * 4 + r;
        int b = row >> 11, t = row & 2047;
        size_t base = ((size_t)(b * 16 + h) * 2048 + t) * 64;
#pragma unroll
        for (int j = 0; j < 2; ++j) {
          int d1 = j * 16 + ln;  // 0..31
          float theta = exp2f((float)d1 * -0.4152410118609203f);  // 10000^(-d1/32)
          float sn, cs;
          fast_sincos((float)t * theta, &sn, &cs);
          float v1 = acc[i][j][r], v2 = acc[i][j + 2][r];
          dst[base + d1]      = f2bf((v1 * cs - v2 * sn) * oscl);
          dst[base + d1 + 32] = f2bf((v2 * cs + v1 * sn) * oscl);
        }
      }
    }
  } else {
    // ---- V: acc -> LDS [d][t] (swizzled) -> coalesced Vt stores ----
    // gemm_core ended with __syncthreads(); Ls is free for reuse.
#pragma unroll
    for (int i = 0; i < 4; ++i)
#pragma unroll
      for (int j = 0; j < 4; ++j) {
        int dl = wn * 64 + j * 16 + ln;           // 0..127 (local d)
        int tb = wm * 64 + i * 16 + quad * 4;     // 0..124 (local t, 4-aligned)
        int tS = tb ^ ((dl & 15) << 3);           // bank swizzle, keeps 4-align
        unsigned lo = (unsigned)f2bf(acc[i][j][0]) | ((unsigned)f2bf(acc[i][j][1]) << 16);
        unsigned hi = (unsigned)f2bf(acc[i][j][2]) | ((unsigned)f2bf(acc[i][j][3]) << 16);
        *(uint2*)(Ls + dl * 128 + tS) = make_uint2(lo, hi);
      }
    __syncthreads();   // safe: seg is block-uniform
    const int dl = tid >> 1;                       // 0..127
    const int hh = ((col0 + dl) & 1023) >> 6;      // head of this d-row
    const int din = dl & 63;
    const int tb = (row0 & 2047) + (tid & 1) * 64; // global t base (b fixed per block)
    const size_t vb = ((size_t)((row0 >> 11) * 16 + hh) * 64 + din) * 2048 + tb;
    const int swz = (dl & 15) << 3;
#pragma unroll
    for (int c = 0; c < 8; ++c) {
      int tl = (tid & 1) * 64 + c * 8;             // local t of this 16B chunk
      v8s v = *(const v8s*)(Ls + dl * 128 + (tl ^ swz));
      *(v8s*)(Vt + vb + c * 8) = v;                // contiguous 128 B per thread
    }
  }
}

// ---------------- output GEMM: 128x64 tiles, 4 blocks/CU ----------------
// (r13: reverted from 128x128 — 512-block grid left 2 blocks/CU, measured
// ~3 us worse than this 1024-block version by r7<->r10 differencing.)
__global__ __launch_bounds__(256, 4) void gemm_out_k(const u16* __restrict__ A,
                                                     const u16* __restrict__ B,
                                                     float* __restrict__ C) {
  __shared__ __align__(16) u16 As[128 * 64];  // 16 KB
  __shared__ __align__(16) u16 Bs[64 * 64];   //  8 KB
  const int tid = threadIdx.x;
  const int lane = tid & 63;
  const int wm = (tid >> 7) & 1;
  const int wn = (tid >> 6) & 1;
  const int ln = lane & 15, quad = lane >> 4;
  const int row0 = blockIdx.x * 128, col0 = blockIdx.y * 64;
  const int K = 1024;
  v4f acc[4][2];
#pragma unroll
  for (int i = 0; i < 4; ++i)
#pragma unroll
    for (int j = 0; j < 2; ++j) acc[i][j] = zero4();
  const int rA = tid >> 3;
  const int cA = (((tid & 7) ^ (rA & 7)) << 3);
  for (int kt = 0; kt < K; kt += 64) {
#pragma unroll
    for (int i = 0; i < 4; ++i)
      async16(A + (size_t)(row0 + i * 32 + rA) * K + kt + cA, As + i * 2048 + tid * 8);
#pragma unroll
    for (int i = 0; i < 2; ++i)
      async16(B + (size_t)(col0 + i * 32 + rA) * K + kt + cA, Bs + i * 2048 + tid * 8);
    __syncthreads();
#pragma unroll
    for (int kk = 0; kk < 2; ++kk) {
      const int go = (((kk * 4 + quad) ^ (ln & 7)) << 3);
      v8s af[4], bfr[2];
#pragma unroll
      for (int i = 0; i < 4; ++i)
        af[i] = *(const v8s*)(As + (wm * 64 + i * 16 + ln) * 64 + go);
#pragma unroll
      for (int j = 0; j < 2; ++j)
        bfr[j] = *(const v8s*)(Bs + (wn * 32 + j * 16 + ln) * 64 + go);
      __builtin_amdgcn_s_setprio(1);
#pragma unroll
      for (int i = 0; i < 4; ++i)
#pragma unroll
        for (int j = 0; j < 2; ++j)
          acc[i][j] = __builtin_amdgcn_mfma_f32_16x16x32_bf16(af[i], bfr[j], acc[i][j], 0, 0, 0);
      __builtin_amdgcn_s_setprio(0);
    }
    __syncthreads();
  }
#pragma unroll
  for (int i = 0; i < 4; ++i)
#pragma unroll
    for (int r = 0; r < 4; ++r) {
      int row = row0 + wm * 64 + i * 16 + quad * 4 + r;
#pragma unroll
      for (int j = 0; j < 2; ++j) {
        int col = col0 + wn * 32 + j * 16 + ln;
        C[(size_t)row * 1024 + col] = acc[i][j][r];
      }
    }
}

// ---------------- causal flash attention v12 (proven, ~79 us) ----------------
template <bool MASKED>
__device__ __forceinline__ void qk_sm_pv(const v8s ak[2][4], const v8s av[2][4],
                                         u16* Pw, const v8s aq[2], v4f od[4],
                                         float& l, int s0, int qrow, int ln,
                                         int quad, int swz) {
  v4f sc[4];
#pragma unroll
  for (int kf = 0; kf < 4; ++kf) sc[kf] = zero4();
#pragma unroll
  for (int kk = 0; kk < 2; ++kk) {
    __builtin_amdgcn_s_setprio(1);
#pragma unroll
    for (int kf = 0; kf < 4; ++kf)
      sc[kf] = __builtin_amdgcn_mfma_f32_16x16x32_bf16(ak[kk][kf], aq[kk], sc[kf], 0, 0, 0);
    __builtin_amdgcn_s_setprio(0);
  }
  float ls = 0.f;
#pragma unroll
  for (int kf = 0; kf < 4; ++kf) {
    float p[4];
#pragma unroll
    for (int r = 0; r < 4; ++r) {
      float v = sc[kf][r];
      if (MASKED) {
        int key = s0 + kf * 16 + quad * 4 + r;
        v = (key <= qrow) ? v : -3.0e38f;   // exp2 -> 0
      }
      p[r] = exp2f(v);
    }
    ls += (p[0] + p[1]) + (p[2] + p[3]);
    uint2 pk;
    pk.x = pk2bf(p[0], p[1]);
    pk.y = pk2bf(p[2], p[3]);
    *(uint2*)(Pw + ln * 64 + (((kf * 4 + quad) ^ swz) << 2)) = pk;
  }
  l += ls;
#pragma unroll
  for (int kk = 0; kk < 2; ++kk) {
    v8s bp = *(const v8s*)(Pw + ln * 64 + (((kk * 8 + quad * 2) ^ swz) << 2));
    __builtin_amdgcn_s_setprio(1);
#pragma unroll
    for (int df = 0; df < 4; ++df)
      od[df] = __builtin_amdgcn_mfma_f32_16x16x32_bf16(av[kk][df], bp, od[df], 0, 0, 0);
    __builtin_amdgcn_s_setprio(0);
  }
}

__device__ __forceinline__ void flash_epi(float l, const v4f od[4], int t,
                                          int b, int h, int quad,
                                          u16* __restrict__ O) {
  float lt = l;
  lt += __shfl_xor(lt, 16);
  lt += __shfl_xor(lt, 32);
  float inv = 1.0f / lt;
  size_t obase = ((size_t)b * 2048 + t) * 1024 + h * 64;
#pragma unroll
  for (int df = 0; df < 4; ++df) {
    ushort4 o;
    o.x = f2bf(od[df][0] * inv);
    o.y = f2bf(od[df][1] * inv);
    o.z = f2bf(od[df][2] * inv);
    o.w = f2bf(od[df][3] * inv);
    *(ushort4*)(O + obase + df * 16 + quad * 4) = o;
  }
}

__global__ __launch_bounds__(256, 2) void flash_k(const u16* __restrict__ Q,
                                                  const u16* __restrict__ Kh,
                                                  const u16* __restrict__ V,
                                                  u16* __restrict__ O) {
  __shared__ __align__(16) u16 Ks[2][4096];
  __shared__ __align__(16) u16 Vs[2][4096];
  __shared__ __align__(16) u16 Ps[4096];
  const int tid = threadIdx.x;
  const int lane = tid & 63, w = tid >> 6;
  const int ln = lane & 15, quad = lane >> 4;
  const int swz = (lane & 7) << 1;
  const int qx = 15 - blockIdx.y;
  const int bh = blockIdx.x;
  const int b = bh >> 4, h = bh & 15;
  const size_t qoff = (size_t)bh * 2048 * 64;
  u16* Pw = Ps + w * 1024;

  const int rS = tid >> 3;
  const int cS = (((tid & 7) ^ (rS & 7)) << 3);
  const u16* Kbase = Kh + qoff;
  const u16* Vbase = V + (size_t)bh * 131072;

  const int nt = 2 * qx + 2;
  const int diag = 2 * qx + (w >> 1);
  const int S0 = qx * 128 + w * 32;
  const int qrow0 = S0 + ln, qrow1 = S0 + 16 + ln;
  v8s aq0[2], aq1[2];
#pragma unroll
  for (int kk = 0; kk < 2; ++kk) {
    aq0[kk] = *(const v8s*)(Q + qoff + (size_t)(S0 + ln) * 64 + kk * 32 + quad * 8);
    aq1[kk] = *(const v8s*)(Q + qoff + (size_t)(S0 + 16 + ln) * 64 + kk * 32 + quad * 8);
  }
  float l0 = 0.f, l1 = 0.f;
  v4f od0[4], od1[4];
#pragma unroll
  for (int df = 0; df < 4; ++df) { od0[df] = zero4(); od1[df] = zero4(); }

  {
    async16(Kbase + (size_t)rS * 64 + cS, Ks[0] + tid * 8);
    async16(Kbase + (size_t)(32 + rS) * 64 + cS, Ks[0] + 2048 + tid * 8);
    async16(Vbase + (size_t)rS * 2048 + cS, Vs[0] + tid * 8);
    async16(Vbase + (size_t)(rS + 32) * 2048 + cS, Vs[0] + 2048 + tid * 8);
  }
  for (int it = 0; it < nt; ++it) {
    __syncthreads();
    if (it + 1 < nt) {
      const int s1 = (it + 1) * 64;
      u16* kd = Ks[(it + 1) & 1];
      u16* vd = Vs[(it + 1) & 1];
      async16(Kbase + (size_t)(s1 + rS) * 64 + cS, kd + tid * 8);
      async16(Kbase + (size_t)(s1 + 32 + rS) * 64 + cS, kd + 2048 + tid * 8);
      async16(Vbase + (size_t)rS * 2048 + s1 + cS, vd + tid * 8);
      async16(Vbase + (size_t)(rS + 32) * 2048 + s1 + cS, vd + 2048 + tid * 8);
    }
    if (it <= diag) {
      const u16* Kc = Ks[it & 1];
      const u16* Vc = Vs[it & 1];
      v8s ak[2][4], av[2][4];
#pragma unroll
      for (int kk = 0; kk < 2; ++kk) {
        const int go = (((kk * 4 + quad) ^ (ln & 7)) << 3);
#pragma unroll
        for (int i = 0; i < 4; ++i) {
          ak[kk][i] = *(const v8s*)(Kc + (i * 16 + ln) * 64 + go);
          av[kk][i] = *(const v8s*)(Vc + (i * 16 + ln) * 64 + go);
        }
      }
      const int s0 = it * 64;
      if (it == diag) {
        qk_sm_pv<true>(ak, av, Pw, aq0, od0, l0, s0, qrow0, ln, quad, swz);
        qk_sm_pv<true>(ak, av, Pw, aq1, od1, l1, s0, qrow1, ln, quad, swz);
      } else {
        qk_sm_pv<false>(ak, av, Pw, aq0, od0, l0, s0, qrow0, ln, quad, swz);
        qk_sm_pv<false>(ak, av, Pw, aq1, od1, l1, s0, qrow1, ln, quad, swz);
      }
    }
  }

  flash_epi(l0, od0, S0 + ln, b, h, quad, O);
  flash_epi(l1, od1, S0 + 16 + ln, b, h, quad, O);
}

extern "C" void kernel_launch(void* const* d_in, const int* in_sizes, int n_in,
                              void* d_out, int out_size, void* d_ws, size_t ws_size,
                              hipStream_t stream) {
  const float* x     = (const float*)d_in[0];
  const float* w_qkv = (const float*)d_in[1];
  const float* w_out = (const float*)d_in[2];
  float* out = (float*)d_out;
  char* ws = (char*)d_ws;
  u16* xb    = (u16*)(ws);              // 16 MB   [0, 16777216)
  u16* wqkvb = (u16*)(ws + 16777216);   // 6 MB    [16777216, 23068672)
  u16* woutb = (u16*)(ws + 23068672);   // 2 MB    [23068672, 25165824)
  u16* qh    = (u16*)(ws + 25165824);   // [64][2048][64]  16 MB
  u16* kh    = (u16*)(ws + 41943040);   // [64][2048][64]  16 MB
  u16* vt    = (u16*)(ws + 58720256);   // [64][64][2048]  16 MB
  u16* oa    = (u16*)(ws + 75497472);   // [8192][1024]    16 MB

  cast_all_k<<<12288, 256, 0, stream>>>(x, w_qkv, w_out, (u16*)ws);
  gemm_qkv_rope<<<dim3(64, 24), 256, 0, stream>>>(xb, wqkvb, qh, kh, vt);
  flash_k<<<dim3(64, 16), 256, 0, stream>>>(qh, kh, vt, oa);
  gemm_out_k<<<dim3(64, 16), 256, 0, stream>>>(oa, woutb, out);
}

// Round 14
// 245.323 us; speedup vs baseline: 1.0577x; 1.0577x over previous
//
#include <hip/hip_runtime.h>

typedef unsigned short u16;
typedef __attribute__((ext_vector_type(8))) short v8s;   // 8 x bf16 MFMA operand
typedef __attribute__((ext_vector_type(4))) float v4f;   // MFMA accumulator

__device__ __forceinline__ u16 f2bf(float f) {
  unsigned u = __float_as_uint(f);
  u += 0x7FFF + ((u >> 16) & 1);   // RNE
  return (u16)(u >> 16);
}

// pack two floats -> {hi.bf16, lo.bf16} u32 (round-half-up, fine at this scale)
__device__ __forceinline__ unsigned pk2bf(float lo, float hi) {
  unsigned a = __float_as_uint(lo) + 0x8000u;
  unsigned b = __float_as_uint(hi) + 0x8000u;
  return __builtin_amdgcn_perm(b, a, 0x07060302);
}

__device__ __forceinline__ v4f zero4() {
  v4f z; z[0] = 0.f; z[1] = 0.f; z[2] = 0.f; z[3] = 0.f; return z;
}

__device__ __forceinline__ void async16(const u16* g, u16* l) {
  __builtin_amdgcn_global_load_lds(
      (const __attribute__((address_space(1))) unsigned int*)g,
      (__attribute__((address_space(3))) unsigned int*)l, 16, 0, 0);
}

// reduce x to [-pi,pi] then native sin/cos (v_sin valid range)
__device__ __forceinline__ void fast_sincos(float x, float* s, float* c) {
  float k = rintf(x * 0.15915494309189535f);
  float r = __builtin_fmaf(k, -6.28125f, x);
  r = __builtin_fmaf(k, -0.0019353071795864769f, r);
  *s = __sinf(r);
  *c = __cosf(r);
}

#define ATTN_SCL (0.125f * 1.4426950408889634f)  // 1/sqrt(64) * log2(e), folded into Q

// ---------------- fused fp32 -> bf16 cast of all three inputs ----------------
__global__ __launch_bounds__(256) void cast_all_k(const float* __restrict__ x,
                                                  const float* __restrict__ wq,
                                                  const float* __restrict__ wo,
                                                  u16* __restrict__ dst) {
  int i = blockIdx.x * 256 + threadIdx.x;
  const float4* s;
  int si;
  if (i < 2097152) { s = (const float4*)x;  si = i; }
  else if (i < 2883584) { s = (const float4*)wq; si = i - 2097152; }
  else { s = (const float4*)wo; si = i - 2883584; }
  float4 v = s[si];
  ((ushort4*)dst)[i] = make_ushort4(f2bf(v.x), f2bf(v.y), f2bf(v.z), f2bf(v.w));
}

// LDS bank swizzle (proven in-session): 16B granule g of row r lives at slot
// g^(r&7); staging loads global granule (slot^(r&7)) into linear LDS slot.

// ---------------- 128x128 GEMM mainloop (shared by qkv and out) --------------
// C(128x128) = A[M,K] @ B[N,K]^T   (both bf16 row-major, K multiple of 64)
__device__ __forceinline__ void gemm_core(const u16* __restrict__ A,
                                          const u16* __restrict__ B, int K,
                                          int row0, int col0, u16* As, u16* Bs,
                                          v4f acc[4][4]) {
  const int tid = threadIdx.x;
  const int lane = tid & 63;
  const int wm = (tid >> 7) & 1;
  const int wn = (tid >> 6) & 1;
  const int ln = lane & 15, quad = lane >> 4;
#pragma unroll
  for (int i = 0; i < 4; ++i)
#pragma unroll
    for (int j = 0; j < 4; ++j) acc[i][j] = zero4();
  const int rA = tid >> 3;
  const int cA = (((tid & 7) ^ (rA & 7)) << 3);   // swizzled source granule
  for (int kt = 0; kt < K; kt += 64) {
#pragma unroll
    for (int i = 0; i < 4; ++i) {
      async16(A + (size_t)(row0 + i * 32 + rA) * K + kt + cA, As + i * 2048 + tid * 8);
      async16(B + (size_t)(col0 + i * 32 + rA) * K + kt + cA, Bs + i * 2048 + tid * 8);
    }
    __syncthreads();
#pragma unroll
    for (int kk = 0; kk < 2; ++kk) {
      const int go = (((kk * 4 + quad) ^ (ln & 7)) << 3);  // swizzled read granule
      v8s af[4], bfr[4];
#pragma unroll
      for (int i = 0; i < 4; ++i) {
        af[i]  = *(const v8s*)(As + (wm * 64 + i * 16 + ln) * 64 + go);
        bfr[i] = *(const v8s*)(Bs + (wn * 64 + i * 16 + ln) * 64 + go);
      }
      __builtin_amdgcn_s_setprio(1);
#pragma unroll
      for (int i = 0; i < 4; ++i)
#pragma unroll
        for (int j = 0; j < 4; ++j)
          acc[i][j] = __builtin_amdgcn_mfma_f32_16x16x32_bf16(af[i], bfr[j], acc[i][j], 0, 0, 0);
      __builtin_amdgcn_s_setprio(0);
    }
    __syncthreads();
  }
}

// ---------------- QKV GEMM + fused RoPE/reshape epilogue ----------------
// q gets the softmax scale folded in (scale commutes with rotation)
__global__ __launch_bounds__(256) void gemm_qkv_rope(const u16* __restrict__ A,
                                                     const u16* __restrict__ B,
                                                     u16* __restrict__ Qh,
                                                     u16* __restrict__ Kh,
                                                     u16* __restrict__ Vt) {
  __shared__ __align__(16) u16 As[8192];
  __shared__ __align__(16) u16 Bs[8192];
  v4f acc[4][4];
  const int row0 = blockIdx.x * 128, col0 = blockIdx.y * 128;
  gemm_core(A, B, 1024, row0, col0, As, Bs, acc);
  const int tid = threadIdx.x, lane = tid & 63;
  const int wm = (tid >> 7) & 1, wn = (tid >> 6) & 1;
  const int ln = lane & 15, quad = lane >> 4;
  const int colbase = col0 + wn * 64;       // 64-aligned => one head per wave
  const int seg = colbase >> 10;            // 0=q 1=k 2=v
  const int h = (colbase & 1023) >> 6;
  if (seg < 2) {
    u16* dst = (seg == 0) ? Qh : Kh;
    const float oscl = (seg == 0) ? ATTN_SCL : 1.0f;
#pragma unroll
    for (int i = 0; i < 4; ++i) {
#pragma unroll
      for (int r = 0; r < 4; ++r) {
        int row = row0 + wm * 64 + i * 16 + quad * 4 + r;
        int b = row >> 11, t = row & 2047;
        size_t base = ((size_t)(b * 16 + h) * 2048 + t) * 64;
#pragma unroll
        for (int j = 0; j < 2; ++j) {
          int d1 = j * 16 + ln;  // 0..31
          float theta = exp2f((float)d1 * -0.4152410118609203f);  // 10000^(-d1/32)
          float sn, cs;
          fast_sincos((float)t * theta, &sn, &cs);
          float v1 = acc[i][j][r], v2 = acc[i][j + 2][r];
          dst[base + d1]      = f2bf((v1 * cs - v2 * sn) * oscl);
          dst[base + d1 + 32] = f2bf((v2 * cs + v1 * sn) * oscl);
        }
      }
    }
  } else {
#pragma unroll
    for (int i = 0; i < 4; ++i)
#pragma unroll
      for (int j = 0; j < 4; ++j) {
        int d = j * 16 + ln;
#pragma unroll
        for (int r = 0; r < 4; ++r) {
          int row = row0 + wm * 64 + i * 16 + quad * 4 + r;
          int b = row >> 11, t = row & 2047;
          Vt[((size_t)(b * 16 + h) * 64 + d) * 2048 + t] = f2bf(acc[i][j][r]);
        }
      }
  }
}

// ---------------- output GEMM: 128x128 tiles via gemm_core ----------------
__global__ __launch_bounds__(256) void gemm_out_k(const u16* __restrict__ A,
                                                  const u16* __restrict__ B,
                                                  float* __restrict__ C) {
  __shared__ __align__(16) u16 As[8192];
  __shared__ __align__(16) u16 Bs[8192];
  v4f acc[4][4];
  const int row0 = blockIdx.x * 128, col0 = blockIdx.y * 128;
  gemm_core(A, B, 1024, row0, col0, As, Bs, acc);
  const int tid = threadIdx.x, lane = tid & 63;
  const int wm = (tid >> 7) & 1, wn = (tid >> 6) & 1;
  const int ln = lane & 15, quad = lane >> 4;
#pragma unroll
  for (int i = 0; i < 4; ++i)
#pragma unroll
    for (int r = 0; r < 4; ++r) {
      int row = row0 + wm * 64 + i * 16 + quad * 4 + r;
#pragma unroll
      for (int j = 0; j < 4; ++j) {
        int col = col0 + wn * 64 + j * 16 + ln;
        C[(size_t)row * 1024 + col] = acc[i][j][r];
      }
    }
}

// ---------------- causal flash attention v12: 2-slice, unpaired, (256,2) -----
// Best measured flash (77.7 us). 128 q-rows/block (4 waves x two 16-row
// slices) halves staged K/V tiles & barriers vs v7b; grid (64 bh x 16 qx)
// unpaired keeps ~3 blocks/CU; bh on blockIdx.x gives XCD-local K/V sharing
// (FETCH 194->30 MB vs v6). RULE (r8/r11): 2-slice state needs >=~160 unified
// VGPR/wave -> never declare tighter than (256,2) or accumulators spill.
// Flash is pinned at ~78-80 us by the per-tile serial chain (QK->exp->pack->
// LDS->PV) across v7b/v9/v10/v11/v12 restructurings.

template <bool MASKED>
__device__ __forceinline__ void qk_sm_pv(const v8s ak[2][4], const v8s av[2][4],
                                         u16* Pw, const v8s aq[2], v4f od[4],
                                         float& l, int s0, int qrow, int ln,
                                         int quad, int swz) {
  v4f sc[4];
#pragma unroll
  for (int kf = 0; kf < 4; ++kf) sc[kf] = zero4();
#pragma unroll
  for (int kk = 0; kk < 2; ++kk) {
    __builtin_amdgcn_s_setprio(1);
#pragma unroll
    for (int kf = 0; kf < 4; ++kf)
      sc[kf] = __builtin_amdgcn_mfma_f32_16x16x32_bf16(ak[kk][kf], aq[kk], sc[kf], 0, 0, 0);
    __builtin_amdgcn_s_setprio(0);
  }
  float ls = 0.f;
#pragma unroll
  for (int kf = 0; kf < 4; ++kf) {
    float p[4];
#pragma unroll
    for (int r = 0; r < 4; ++r) {
      float v = sc[kf][r];
      if (MASKED) {
        int key = s0 + kf * 16 + quad * 4 + r;
        v = (key <= qrow) ? v : -3.0e38f;   // exp2 -> 0
      }
      p[r] = exp2f(v);
    }
    ls += (p[0] + p[1]) + (p[2] + p[3]);
    uint2 pk;
    pk.x = pk2bf(p[0], p[1]);
    pk.y = pk2bf(p[2], p[3]);
    *(uint2*)(Pw + ln * 64 + (((kf * 4 + quad) ^ swz) << 2)) = pk;
  }
  l += ls;
  // PV: per-wave P round-trip (lgkmcnt only, no barrier); V frags from regs
#pragma unroll
  for (int kk = 0; kk < 2; ++kk) {
    v8s bp = *(const v8s*)(Pw + ln * 64 + (((kk * 8 + quad * 2) ^ swz) << 2));
    __builtin_amdgcn_s_setprio(1);
#pragma unroll
    for (int df = 0; df < 4; ++df)
      od[df] = __builtin_amdgcn_mfma_f32_16x16x32_bf16(av[kk][df], bp, od[df], 0, 0, 0);
    __builtin_amdgcn_s_setprio(0);
  }
}

__device__ __forceinline__ void flash_epi(float l, const v4f od[4], int t,
                                          int b, int h, int quad,
                                          u16* __restrict__ O) {
  float lt = l;
  lt += __shfl_xor(lt, 16);
  lt += __shfl_xor(lt, 32);
  float inv = 1.0f / lt;
  size_t obase = ((size_t)b * 2048 + t) * 1024 + h * 64;
#pragma unroll
  for (int df = 0; df < 4; ++df) {
    ushort4 o;
    o.x = f2bf(od[df][0] * inv);
    o.y = f2bf(od[df][1] * inv);
    o.z = f2bf(od[df][2] * inv);
    o.w = f2bf(od[df][3] * inv);
    *(ushort4*)(O + obase + df * 16 + quad * 4) = o;
  }
}

__global__ __launch_bounds__(256, 2) void flash_k(const u16* __restrict__ Q,
                                                  const u16* __restrict__ Kh,
                                                  const u16* __restrict__ V,
                                                  u16* __restrict__ O) {
  __shared__ __align__(16) u16 Ks[2][4096];  // 2 x 8 KB, swizzled
  __shared__ __align__(16) u16 Vs[2][4096];  // 2 x 8 KB, swizzled
  __shared__ __align__(16) u16 Ps[4096];     // 8 KB (4 waves x 2 KB, swizzled)
  const int tid = threadIdx.x;
  const int lane = tid & 63, w = tid >> 6;
  const int ln = lane & 15, quad = lane >> 4;
  const int swz = (lane & 7) << 1;           // even -> preserves 16B pairs
  const int qx = 15 - blockIdx.y;            // big blocks dispatch first
  const int bh = blockIdx.x;                 // bh on x: XCD-local K/V sharing
  const int b = bh >> 4, h = bh & 15;
  const size_t qoff = (size_t)bh * 2048 * 64;
  u16* Pw = Ps + w * 1024;

  const int rS = tid >> 3;                   // 0..31
  const int cS = (((tid & 7) ^ (rS & 7)) << 3);   // swizzled source granule
  const u16* Kbase = Kh + qoff;
  const u16* Vbase = V + (size_t)bh * 131072;

  const int nt = 2 * qx + 2;                 // k-tiles needed by this q-block
  const int diag = 2 * qx + (w >> 1);        // this wave's diagonal tile
  const int S0 = qx * 128 + w * 32;          // slice0 rows S0..S0+15, slice1 +16
  const int qrow0 = S0 + ln, qrow1 = S0 + 16 + ln;
  v8s aq0[2], aq1[2];
#pragma unroll
  for (int kk = 0; kk < 2; ++kk) {
    aq0[kk] = *(const v8s*)(Q + qoff + (size_t)(S0 + ln) * 64 + kk * 32 + quad * 8);
    aq1[kk] = *(const v8s*)(Q + qoff + (size_t)(S0 + 16 + ln) * 64 + kk * 32 + quad * 8);
  }
  float l0 = 0.f, l1 = 0.f;
  v4f od0[4], od1[4];
#pragma unroll
  for (int df = 0; df < 4; ++df) { od0[df] = zero4(); od1[df] = zero4(); }

  // prologue: stage tile 0 into buffer 0
  {
    async16(Kbase + (size_t)rS * 64 + cS, Ks[0] + tid * 8);
    async16(Kbase + (size_t)(32 + rS) * 64 + cS, Ks[0] + 2048 + tid * 8);
    async16(Vbase + (size_t)rS * 2048 + cS, Vs[0] + tid * 8);
    async16(Vbase + (size_t)(rS + 32) * 2048 + cS, Vs[0] + 2048 + tid * 8);
  }
  for (int it = 0; it < nt; ++it) {
    __syncthreads();  // drains prefetch of buf[it&1]; guards reuse of buf[(it+1)&1]
    if (it + 1 < nt) {
      const int s1 = (it + 1) * 64;
      u16* kd = Ks[(it + 1) & 1];
      u16* vd = Vs[(it + 1) & 1];
      async16(Kbase + (size_t)(s1 + rS) * 64 + cS, kd + tid * 8);
      async16(Kbase + (size_t)(s1 + 32 + rS) * 64 + cS, kd + 2048 + tid * 8);
      async16(Vbase + (size_t)rS * 2048 + s1 + cS, vd + tid * 8);
      async16(Vbase + (size_t)(rS + 32) * 2048 + s1 + cS, vd + 2048 + tid * 8);
    }
    if (it <= diag) {  // wave-uniform; keys beyond diag are fully masked
      const u16* Kc = Ks[it & 1];
      const u16* Vc = Vs[it & 1];
      v8s ak[2][4], av[2][4];
#pragma unroll
      for (int kk = 0; kk < 2; ++kk) {
        const int go = (((kk * 4 + quad) ^ (ln & 7)) << 3);
#pragma unroll
        for (int i = 0; i < 4; ++i) {
          ak[kk][i] = *(const v8s*)(Kc + (i * 16 + ln) * 64 + go);
          av[kk][i] = *(const v8s*)(Vc + (i * 16 + ln) * 64 + go);
        }
      }
      const int s0 = it * 64;
      if (it == diag) {
        qk_sm_pv<true>(ak, av, Pw, aq0, od0, l0, s0, qrow0, ln, quad, swz);
        qk_sm_pv<true>(ak, av, Pw, aq1, od1, l1, s0, qrow1, ln, quad, swz);
      } else {
        qk_sm_pv<false>(ak, av, Pw, aq0, od0, l0, s0, qrow0, ln, quad, swz);
        qk_sm_pv<false>(ak, av, Pw, aq1, od1, l1, s0, qrow1, ln, quad, swz);
      }
    }
  }

  flash_epi(l0, od0, S0 + ln, b, h, quad, O);
  flash_epi(l1, od1, S0 + 16 + ln, b, h, quad, O);
}

extern "C" void kernel_launch(void* const* d_in, const int* in_sizes, int n_in,
                              void* d_out, int out_size, void* d_ws, size_t ws_size,
                              hipStream_t stream) {
  const float* x     = (const float*)d_in[0];
  const float* w_qkv = (const float*)d_in[1];
  const float* w_out = (const float*)d_in[2];
  float* out = (float*)d_out;
  char* ws = (char*)d_ws;
  u16* xb    = (u16*)(ws);              // 16 MB   [0, 16777216)
  u16* wqkvb = (u16*)(ws + 16777216);   // 6 MB    [16777216, 23068672)
  u16* woutb = (u16*)(ws + 23068672);   // 2 MB    [23068672, 25165824)
  u16* qh    = (u16*)(ws + 25165824);   // [64][2048][64]  16 MB
  u16* kh    = (u16*)(ws + 41943040);   // [64][2048][64]  16 MB
  u16* vt    = (u16*)(ws + 58720256);   // [64][64][2048]  16 MB
  u16* oa    = (u16*)(ws + 75497472);   // [8192][1024]    16 MB

  cast_all_k<<<12288, 256, 0, stream>>>(x, w_qkv, w_out, (u16*)ws);
  gemm_qkv_rope<<<dim3(64, 24), 256, 0, stream>>>(xb, wqkvb, qh, kh, vt);
  flash_k<<<dim3(64, 16), 256, 0, stream>>>(qh, kh, vt, oa);
  gemm_out_k<<<dim3(64, 8), 256, 0, stream>>>(oa, woutb, out);
}

// Round 15
// 238.588 us; speedup vs baseline: 1.0875x; 1.0282x over previous
//
#include <hip/hip_runtime.h>

typedef unsigned short u16;
typedef __attribute__((ext_vector_type(8))) short v8s;   // 8 x bf16 MFMA operand
typedef __attribute__((ext_vector_type(4))) float v4f;   // MFMA accumulator

__device__ __forceinline__ u16 f2bf(float f) {
  unsigned u = __float_as_uint(f);
  u += 0x7FFF + ((u >> 16) & 1);   // RNE
  return (u16)(u >> 16);
}

// pack two floats -> {hi.bf16, lo.bf16} u32 (round-half-up, fine at this scale)
__device__ __forceinline__ unsigned pk2bf(float lo, float hi) {
  unsigned a = __float_as_uint(lo) + 0x8000u;
  unsigned b = __float_as_uint(hi) + 0x8000u;
  return __builtin_amdgcn_perm(b, a, 0x07060302);
}

__device__ __forceinline__ v4f zero4() {
  v4f z; z[0] = 0.f; z[1] = 0.f; z[2] = 0.f; z[3] = 0.f; return z;
}

__device__ __forceinline__ void async16(const u16* g, u16* l) {
  __builtin_amdgcn_global_load_lds(
      (const __attribute__((address_space(1))) unsigned int*)g,
      (__attribute__((address_space(3))) unsigned int*)l, 16, 0, 0);
}

// reduce x to [-pi,pi] then native sin/cos (v_sin valid range)
__device__ __forceinline__ void fast_sincos(float x, float* s, float* c) {
  float k = rintf(x * 0.15915494309189535f);
  float r = __builtin_fmaf(k, -6.28125f, x);
  r = __builtin_fmaf(k, -0.0019353071795864769f, r);
  *s = __sinf(r);
  *c = __cosf(r);
}

#define ATTN_SCL (0.125f * 1.4426950408889634f)  // 1/sqrt(64) * log2(e), folded into Q

// ---------------- fused fp32 -> bf16 cast of all three inputs ----------------
__global__ __launch_bounds__(256) void cast_all_k(const float* __restrict__ x,
                                                  const float* __restrict__ wq,
                                                  const float* __restrict__ wo,
                                                  u16* __restrict__ dst) {
  int i = blockIdx.x * 256 + threadIdx.x;
  const float4* s;
  int si;
  if (i < 2097152) { s = (const float4*)x;  si = i; }
  else if (i < 2883584) { s = (const float4*)wq; si = i - 2097152; }
  else { s = (const float4*)wo; si = i - 2883584; }
  float4 v = s[si];
  ((ushort4*)dst)[i] = make_ushort4(f2bf(v.x), f2bf(v.y), f2bf(v.z), f2bf(v.w));
}

// LDS bank swizzle (proven in-session): 16B granule g of row r lives at slot
// g^(r&7); staging loads global granule (slot^(r&7)) into linear LDS slot.

// ---------------- 128x128 GEMM mainloop (shared by qkv and out) --------------
// C(128x128) = A[M,K] @ B[N,K]^T   (both bf16 row-major, K multiple of 64)
__device__ __forceinline__ void gemm_core(const u16* __restrict__ A,
                                          const u16* __restrict__ B, int K,
                                          int row0, int col0, u16* As, u16* Bs,
                                          v4f acc[4][4]) {
  const int tid = threadIdx.x;
  const int lane = tid & 63;
  const int wm = (tid >> 7) & 1;
  const int wn = (tid >> 6) & 1;
  const int ln = lane & 15, quad = lane >> 4;
#pragma unroll
  for (int i = 0; i < 4; ++i)
#pragma unroll
    for (int j = 0; j < 4; ++j) acc[i][j] = zero4();
  const int rA = tid >> 3;
  const int cA = (((tid & 7) ^ (rA & 7)) << 3);   // swizzled source granule
  for (int kt = 0; kt < K; kt += 64) {
#pragma unroll
    for (int i = 0; i < 4; ++i) {
      async16(A + (size_t)(row0 + i * 32 + rA) * K + kt + cA, As + i * 2048 + tid * 8);
      async16(B + (size_t)(col0 + i * 32 + rA) * K + kt + cA, Bs + i * 2048 + tid * 8);
    }
    __syncthreads();
#pragma unroll
    for (int kk = 0; kk < 2; ++kk) {
      const int go = (((kk * 4 + quad) ^ (ln & 7)) << 3);  // swizzled read granule
      v8s af[4], bfr[4];
#pragma unroll
      for (int i = 0; i < 4; ++i) {
        af[i]  = *(const v8s*)(As + (wm * 64 + i * 16 + ln) * 64 + go);
        bfr[i] = *(const v8s*)(Bs + (wn * 64 + i * 16 + ln) * 64 + go);
      }
      __builtin_amdgcn_s_setprio(1);
#pragma unroll
      for (int i = 0; i < 4; ++i)
#pragma unroll
        for (int j = 0; j < 4; ++j)
          acc[i][j] = __builtin_amdgcn_mfma_f32_16x16x32_bf16(af[i], bfr[j], acc[i][j], 0, 0, 0);
      __builtin_amdgcn_s_setprio(0);
    }
    __syncthreads();
  }
}

// ---------------- QKV GEMM + fused RoPE/reshape epilogue ----------------
// q gets the softmax scale folded in (scale commutes with rotation)
__global__ __launch_bounds__(256) void gemm_qkv_rope(const u16* __restrict__ A,
                                                     const u16* __restrict__ B,
                                                     u16* __restrict__ Qh,
                                                     u16* __restrict__ Kh,
                                                     u16* __restrict__ Vt) {
  __shared__ __align__(16) u16 As[8192];
  __shared__ __align__(16) u16 Bs[8192];
  v4f acc[4][4];
  const int row0 = blockIdx.x * 128, col0 = blockIdx.y * 128;
  gemm_core(A, B, 1024, row0, col0, As, Bs, acc);
  const int tid = threadIdx.x, lane = tid & 63;
  const int wm = (tid >> 7) & 1, wn = (tid >> 6) & 1;
  const int ln = lane & 15, quad = lane >> 4;
  const int colbase = col0 + wn * 64;       // 64-aligned => one head per wave
  const int seg = colbase >> 10;            // 0=q 1=k 2=v
  const int h = (colbase & 1023) >> 6;
  if (seg < 2) {
    u16* dst = (seg == 0) ? Qh : Kh;
    const float oscl = (seg == 0) ? ATTN_SCL : 1.0f;
#pragma unroll
    for (int i = 0; i < 4; ++i) {
#pragma unroll
      for (int r = 0; r < 4; ++r) {
        int row = row0 + wm * 64 + i * 16 + quad * 4 + r;
        int b = row >> 11, t = row & 2047;
        size_t base = ((size_t)(b * 16 + h) * 2048 + t) * 64;
#pragma unroll
        for (int j = 0; j < 2; ++j) {
          int d1 = j * 16 + ln;  // 0..31
          float theta = exp2f((float)d1 * -0.4152410118609203f);  // 10000^(-d1/32)
          float sn, cs;
          fast_sincos((float)t * theta, &sn, &cs);
          float v1 = acc[i][j][r], v2 = acc[i][j + 2][r];
          dst[base + d1]      = f2bf((v1 * cs - v2 * sn) * oscl);
          dst[base + d1 + 32] = f2bf((v2 * cs + v1 * sn) * oscl);
        }
      }
    }
  } else {
#pragma unroll
    for (int i = 0; i < 4; ++i)
#pragma unroll
      for (int j = 0; j < 4; ++j) {
        int d = j * 16 + ln;
#pragma unroll
        for (int r = 0; r < 4; ++r) {
          int row = row0 + wm * 64 + i * 16 + quad * 4 + r;
          int b = row >> 11, t = row & 2047;
          Vt[((size_t)(b * 16 + h) * 64 + d) * 2048 + t] = f2bf(acc[i][j][r]);
        }
      }
  }
}

// ---------------- output GEMM: 128x128 tiles via gemm_core ----------------
__global__ __launch_bounds__(256) void gemm_out_k(const u16* __restrict__ A,
                                                  const u16* __restrict__ B,
                                                  float* __restrict__ C) {
  __shared__ __align__(16) u16 As[8192];
  __shared__ __align__(16) u16 Bs[8192];
  v4f acc[4][4];
  const int row0 = blockIdx.x * 128, col0 = blockIdx.y * 128;
  gemm_core(A, B, 1024, row0, col0, As, Bs, acc);
  const int tid = threadIdx.x, lane = tid & 63;
  const int wm = (tid >> 7) & 1, wn = (tid >> 6) & 1;
  const int ln = lane & 15, quad = lane >> 4;
#pragma unroll
  for (int i = 0; i < 4; ++i)
#pragma unroll
    for (int r = 0; r < 4; ++r) {
      int row = row0 + wm * 64 + i * 16 + quad * 4 + r;
#pragma unroll
      for (int j = 0; j < 4; ++j) {
        int col = col0 + wn * 64 + j * 16 + ln;
        C[(size_t)row * 1024 + col] = acc[i][j][r];
      }
    }
}

// ---------------- causal flash attention v13: slice-overlapped v12 ----------
// v12 post-analysis: both slices shared ONE Pw region, so slice1's P-writes
// serialized behind slice0's PV P-reads (in-order DS pipe) -> the per-tile
// chain was fully sequential. v13 gives each slice its own P region (Ps 8->16
// KB, LDS 40->48 KB, 3 blocks/CU) and interleaves at source:
//   QK0||QK1 (16 MFMA) -> SM0->Pw0 -> SM1->Pw1 -> PV0 -> PV1
// With disjoint buffers the scheduler overlaps SM1's exp/pack VALU under
// PV0's ds_read+MFMA (counted lgkmcnt, no drain) — hides ~1 softmax/tile.
// Per-slice arithmetic and accumulation order identical to v12 -> absmax
// must stay exactly 0.01757812. RULE (r8/r11): never declare tighter than
// (256,2) — 2-slice state (~190 unified VGPR) spills under a 128 cap.

template <bool MASKED>
__device__ __forceinline__ void qk_sm_pv2(const v8s ak[2][4], const v8s av[2][4],
                                          u16* Pw0, u16* Pw1,
                                          const v8s aq0[2], const v8s aq1[2],
                                          v4f od0[4], v4f od1[4],
                                          float& l0, float& l1,
                                          int s0, int qrow0, int qrow1,
                                          int ln, int quad, int swz) {
  v4f sc0[4], sc1[4];
#pragma unroll
  for (int kf = 0; kf < 4; ++kf) { sc0[kf] = zero4(); sc1[kf] = zero4(); }
  // ---- QK^T, both slices (same ak operands, independent aq/acc) ----
#pragma unroll
  for (int kk = 0; kk < 2; ++kk) {
    __builtin_amdgcn_s_setprio(1);
#pragma unroll
    for (int kf = 0; kf < 4; ++kf) {
      sc0[kf] = __builtin_amdgcn_mfma_f32_16x16x32_bf16(ak[kk][kf], aq0[kk], sc0[kf], 0, 0, 0);
      sc1[kf] = __builtin_amdgcn_mfma_f32_16x16x32_bf16(ak[kk][kf], aq1[kk], sc1[kf], 0, 0, 0);
    }
    __builtin_amdgcn_s_setprio(0);
  }
  // ---- softmax slice0 -> Pw0 ----
  float ls0 = 0.f;
#pragma unroll
  for (int kf = 0; kf < 4; ++kf) {
    float p[4];
#pragma unroll
    for (int r = 0; r < 4; ++r) {
      float v = sc0[kf][r];
      if (MASKED) {
        int key = s0 + kf * 16 + quad * 4 + r;
        v = (key <= qrow0) ? v : -3.0e38f;   // exp2 -> 0
      }
      p[r] = exp2f(v);
    }
    ls0 += (p[0] + p[1]) + (p[2] + p[3]);
    uint2 pk;
    pk.x = pk2bf(p[0], p[1]);
    pk.y = pk2bf(p[2], p[3]);
    *(uint2*)(Pw0 + ln * 64 + (((kf * 4 + quad) ^ swz) << 2)) = pk;
  }
  l0 += ls0;
  // ---- softmax slice1 -> Pw1 (independent; overlaps PV0 below) ----
  float ls1 = 0.f;
#pragma unroll
  for (int kf = 0; kf < 4; ++kf) {
    float p[4];
#pragma unroll
    for (int r = 0; r < 4; ++r) {
      float v = sc1[kf][r];
      if (MASKED) {
        int key = s0 + kf * 16 + quad * 4 + r;
        v = (key <= qrow1) ? v : -3.0e38f;
      }
      p[r] = exp2f(v);
    }
    ls1 += (p[0] + p[1]) + (p[2] + p[3]);
    uint2 pk;
    pk.x = pk2bf(p[0], p[1]);
    pk.y = pk2bf(p[2], p[3]);
    *(uint2*)(Pw1 + ln * 64 + (((kf * 4 + quad) ^ swz) << 2)) = pk;
  }
  l1 += ls1;
  // ---- PV slice0 (reads Pw0 only; V frags from regs) ----
#pragma unroll
  for (int kk = 0; kk < 2; ++kk) {
    v8s bp = *(const v8s*)(Pw0 + ln * 64 + (((kk * 8 + quad * 2) ^ swz) << 2));
    __builtin_amdgcn_s_setprio(1);
#pragma unroll
    for (int df = 0; df < 4; ++df)
      od0[df] = __builtin_amdgcn_mfma_f32_16x16x32_bf16(av[kk][df], bp, od0[df], 0, 0, 0);
    __builtin_amdgcn_s_setprio(0);
  }
  // ---- PV slice1 ----
#pragma unroll
  for (int kk = 0; kk < 2; ++kk) {
    v8s bp = *(const v8s*)(Pw1 + ln * 64 + (((kk * 8 + quad * 2) ^ swz) << 2));
    __builtin_amdgcn_s_setprio(1);
#pragma unroll
    for (int df = 0; df < 4; ++df)
      od1[df] = __builtin_amdgcn_mfma_f32_16x16x32_bf16(av[kk][df], bp, od1[df], 0, 0, 0);
    __builtin_amdgcn_s_setprio(0);
  }
}

__device__ __forceinline__ void flash_epi(float l, const v4f od[4], int t,
                                          int b, int h, int quad,
                                          u16* __restrict__ O) {
  float lt = l;
  lt += __shfl_xor(lt, 16);
  lt += __shfl_xor(lt, 32);
  float inv = 1.0f / lt;
  size_t obase = ((size_t)b * 2048 + t) * 1024 + h * 64;
#pragma unroll
  for (int df = 0; df < 4; ++df) {
    ushort4 o;
    o.x = f2bf(od[df][0] * inv);
    o.y = f2bf(od[df][1] * inv);
    o.z = f2bf(od[df][2] * inv);
    o.w = f2bf(od[df][3] * inv);
    *(ushort4*)(O + obase + df * 16 + quad * 4) = o;
  }
}

__global__ __launch_bounds__(256, 2) void flash_k(const u16* __restrict__ Q,
                                                  const u16* __restrict__ Kh,
                                                  const u16* __restrict__ V,
                                                  u16* __restrict__ O) {
  __shared__ __align__(16) u16 Ks[2][4096];  // 2 x 8 KB, swizzled
  __shared__ __align__(16) u16 Vs[2][4096];  // 2 x 8 KB, swizzled
  __shared__ __align__(16) u16 Ps[8192];     // 16 KB (4 waves x 2 slices x 2 KB)
  const int tid = threadIdx.x;
  const int lane = tid & 63, w = tid >> 6;
  const int ln = lane & 15, quad = lane >> 4;
  const int swz = (lane & 7) << 1;           // even -> preserves 16B pairs
  const int qx = 15 - blockIdx.y;            // big blocks dispatch first
  const int bh = blockIdx.x;                 // bh on x: XCD-local K/V sharing
  const int b = bh >> 4, h = bh & 15;
  const size_t qoff = (size_t)bh * 2048 * 64;
  u16* Pw0 = Ps + w * 2048;
  u16* Pw1 = Pw0 + 1024;

  const int rS = tid >> 3;                   // 0..31
  const int cS = (((tid & 7) ^ (rS & 7)) << 3);   // swizzled source granule
  const u16* Kbase = Kh + qoff;
  const u16* Vbase = V + (size_t)bh * 131072;

  const int nt = 2 * qx + 2;                 // k-tiles needed by this q-block
  const int diag = 2 * qx + (w >> 1);        // this wave's diagonal tile
  const int S0 = qx * 128 + w * 32;          // slice0 rows S0..S0+15, slice1 +16
  const int qrow0 = S0 + ln, qrow1 = S0 + 16 + ln;
  v8s aq0[2], aq1[2];
#pragma unroll
  for (int kk = 0; kk < 2; ++kk) {
    aq0[kk] = *(const v8s*)(Q + qoff + (size_t)(S0 + ln) * 64 + kk * 32 + quad * 8);
    aq1[kk] = *(const v8s*)(Q + qoff + (size_t)(S0 + 16 + ln) * 64 + kk * 32 + quad * 8);
  }
  float l0 = 0.f, l1 = 0.f;
  v4f od0[4], od1[4];
#pragma unroll
  for (int df = 0; df < 4; ++df) { od0[df] = zero4(); od1[df] = zero4(); }

  // prologue: stage tile 0 into buffer 0
  {
    async16(Kbase + (size_t)rS * 64 + cS, Ks[0] + tid * 8);
    async16(Kbase + (size_t)(32 + rS) * 64 + cS, Ks[0] + 2048 + tid * 8);
    async16(Vbase + (size_t)rS * 2048 + cS, Vs[0] + tid * 8);
    async16(Vbase + (size_t)(rS + 32) * 2048 + cS, Vs[0] + 2048 + tid * 8);
  }
  for (int it = 0; it < nt; ++it) {
    __syncthreads();  // drains prefetch of buf[it&1]; guards reuse of buf[(it+1)&1]
    if (it + 1 < nt) {
      const int s1 = (it + 1) * 64;
      u16* kd = Ks[(it + 1) & 1];
      u16* vd = Vs[(it + 1) & 1];
      async16(Kbase + (size_t)(s1 + rS) * 64 + cS, kd + tid * 8);
      async16(Kbase + (size_t)(s1 + 32 + rS) * 64 + cS, kd + 2048 + tid * 8);
      async16(Vbase + (size_t)rS * 2048 + s1 + cS, vd + tid * 8);
      async16(Vbase + (size_t)(rS + 32) * 2048 + s1 + cS, vd + 2048 + tid * 8);
    }
    if (it <= diag) {  // wave-uniform; keys beyond diag are fully masked
      const u16* Kc = Ks[it & 1];
      const u16* Vc = Vs[it & 1];
      v8s ak[2][4], av[2][4];
#pragma unroll
      for (int kk = 0; kk < 2; ++kk) {
        const int go = (((kk * 4 + quad) ^ (ln & 7)) << 3);
#pragma unroll
        for (int i = 0; i < 4; ++i) {
          ak[kk][i] = *(const v8s*)(Kc + (i * 16 + ln) * 64 + go);
          av[kk][i] = *(const v8s*)(Vc + (i * 16 + ln) * 64 + go);
        }
      }
      const int s0 = it * 64;
      if (it == diag) {
        qk_sm_pv2<true>(ak, av, Pw0, Pw1, aq0, aq1, od0, od1, l0, l1,
                        s0, qrow0, qrow1, ln, quad, swz);
      } else {
        qk_sm_pv2<false>(ak, av, Pw0, Pw1, aq0, aq1, od0, od1, l0, l1,
                         s0, qrow0, qrow1, ln, quad, swz);
      }
    }
  }

  flash_epi(l0, od0, S0 + ln, b, h, quad, O);
  flash_epi(l1, od1, S0 + 16 + ln, b, h, quad, O);
}

extern "C" void kernel_launch(void* const* d_in, const int* in_sizes, int n_in,
                              void* d_out, int out_size, void* d_ws, size_t ws_size,
                              hipStream_t stream) {
  const float* x     = (const float*)d_in[0];
  const float* w_qkv = (const float*)d_in[1];
  const float* w_out = (const float*)d_in[2];
  float* out = (float*)d_out;
  char* ws = (char*)d_ws;
  u16* xb    = (u16*)(ws);              // 16 MB   [0, 16777216)
  u16* wqkvb = (u16*)(ws + 16777216);   // 6 MB    [16777216, 23068672)
  u16* woutb = (u16*)(ws + 23068672);   // 2 MB    [23068672, 25165824)
  u16* qh    = (u16*)(ws + 25165824);   // [64][2048][64]  16 MB
  u16* kh    = (u16*)(ws + 41943040);   // [64][2048][64]  16 MB
  u16* vt    = (u16*)(ws + 58720256);   // [64][64][2048]  16 MB
  u16* oa    = (u16*)(ws + 75497472);   // [8192][1024]    16 MB

  cast_all_k<<<12288, 256, 0, stream>>>(x, w_qkv, w_out, (u16*)ws);
  gemm_qkv_rope<<<dim3(64, 24), 256, 0, stream>>>(xb, wqkvb, qh, kh, vt);
  flash_k<<<dim3(64, 16), 256, 0, stream>>>(qh, kh, vt, oa);
  gemm_out_k<<<dim3(64, 8), 256, 0, stream>>>(oa, woutb, out);
}